// Round 9
// baseline (135.576 us; speedup 1.0000x reference)
//
#include <hip/hip_runtime.h>

// VQ-VAE quantize. Output BIT-EXACT vs numpy fp32 pipeline (proven R3-R8):
//   d_k = fl32( fl32(sumx + sume_k) - c_k ), c_k = sequential-k fp32 FMA of (2x).e,
//   idx = first-minimum argmin.
//
// R9: ONE MFMA sweep (was two). Operand swap: mfma(A=e_frag, B=x_frag) gives
// D[k][x-row] so each lane's 4 acc regs are 4 k-values of ONE row; per-row
// running min lives in the 4-lane xor{16,32} group (2 shfl/strip/tile).
// Candidates appended online: s~ < runmin_row + W, W = SA*1.6e-5 + 4e-5
// (superset of R8's set since runmin >= final min -> same exactness guarantee).
// Double-buffered staging (loads issued one chunk ahead, 1 barrier/chunk).
// Lane-parallel exact rescore of worklist; first-min via fkey/k atomicMin.

#define N_ROWS   131072
#define NUM_EMB  1024
#define EMB_DIM  64
#define Q_ELEMS  8388608
#define THREADS  512
#define ROWS_PB  256          // 8 waves x 32 rows
#define KCHUNK   128
#define NCHUNKS  8
#define WCAP     6144

typedef short short8 __attribute__((ext_vector_type(8)));
typedef float f32x4  __attribute__((ext_vector_type(4)));

__device__ __forceinline__ unsigned short bf16_rne(float f) {
    unsigned u = __float_as_uint(f);
    u += 0x7fffu + ((u >> 16) & 1u);
    return (unsigned short)(u >> 16);
}

// monotone key for f32 (handles negatives): smaller float -> smaller key
__device__ __forceinline__ unsigned fkey(float d) {
    unsigned b = __float_as_uint(d);
    return b ^ (((unsigned)((int)b >> 31)) | 0x80000000u);
}

// numpy pairwise_sum (n=64) of fl32(a[i]*a[i]) — 8-accumulator order.
__device__ __forceinline__ float np_sq64(const float* a) {
    #pragma clang fp contract(off)
    float r0=a[0]*a[0],r1=a[1]*a[1],r2=a[2]*a[2],r3=a[3]*a[3];
    float r4=a[4]*a[4],r5=a[5]*a[5],r6=a[6]*a[6],r7=a[7]*a[7];
    #pragma unroll
    for (int i=8;i<64;i+=8){
        r0+=a[i+0]*a[i+0];r1+=a[i+1]*a[i+1];r2+=a[i+2]*a[i+2];r3+=a[i+3]*a[i+3];
        r4+=a[i+4]*a[i+4];r5+=a[i+5]*a[i+5];r6+=a[i+6]*a[i+6];r7+=a[i+7]*a[i+7];
    }
    return ((r0+r1)+(r2+r3))+((r4+r5)+(r6+r7));
}

// prep: sume (np order) + emb -> bf16, layout unit = chunk*1024 + gp*128 + krow
// (unit = 8 bf16 of dims gp*8..gp*8+7). Unchanged from R8 (verified).
__global__ __launch_bounds__(256) void vq_prep(const float* __restrict__ emb,
                                               float* __restrict__ sume,
                                               unsigned short* __restrict__ ehg) {
    int k = blockIdx.x * 256 + threadIdx.x;
    if (k < NUM_EMB) {
        sume[k] = np_sq64(emb + (k << 6));
        int c = k >> 7, krow = k & 127;
        #pragma unroll
        for (int gp = 0; gp < 8; ++gp) {
            short8 h;
            #pragma unroll
            for (int j = 0; j < 8; ++j)
                h[j] = (short)bf16_rne(emb[(k << 6) + gp*8 + j]);
            reinterpret_cast<short8*>(ehg)[c*1024 + gp*128 + krow] = h;
        }
    }
}

__global__ __launch_bounds__(THREADS, 2)
void vq_main(const float* __restrict__ x, const float* __restrict__ emb,
             const float* __restrict__ sume_g, const unsigned short* __restrict__ ehg,
             float* __restrict__ out_q, float* __restrict__ out_idx) {
    __shared__ int4     EH4[2][1024];     // 32 KB double-buffered e-chunks
    __shared__ float    SUME[NUM_EMB];    // 4 KB
    __shared__ int      WL[WCAP];         // 24 KB worklist (row<<10 | k)
    __shared__ unsigned DMIN[ROWS_PB];
    __shared__ unsigned KMIN[ROWS_PB];
    __shared__ int      SIDX[ROWS_PB];
    __shared__ unsigned WCNT;

    const int t   = threadIdx.x;
    const int w   = t >> 6;
    const int l   = t & 63;
    const int g   = l >> 4;
    const int c16 = l & 15;
    const size_t blk_row0 = (size_t)blockIdx.x * ROWS_PB;

    SUME[t]       = sume_g[t];
    SUME[t + 512] = sume_g[t + 512];
    if (t < ROWS_PB) { DMIN[t] = 0xFFFFFFFFu; KMIN[t] = 0xFFFFFFFFu; }
    if (t == 0) WCNT = 0u;

    // ---- x-frags as B-operand (R8-verified layout: B[kd][n], n=lane&15=x-row,
    // kd=8*(lane>>4)+j), 2.0 folded in; per-row W from SA = sum|2x| (4-lane group).
    short8 ah[2][2];
    float  thr[2];
    #pragma unroll
    for (int s = 0; s < 2; ++s) {
        const float* xp = x + (blk_row0 + (size_t)(w*32 + s*16 + c16)) * EMB_DIM;
        float sabs = 0.f;
        #pragma unroll
        for (int hf = 0; hf < 2; ++hf) {
            #pragma unroll
            for (int j = 0; j < 8; ++j) {
                float v = 2.0f * xp[hf*32 + g*8 + j];
                sabs += fabsf(v);
                ah[s][hf][j] = (short)bf16_rne(v);
            }
        }
        sabs += __shfl_xor(sabs, 16);
        sabs += __shfl_xor(sabs, 32);
        thr[s] = sabs * 1.6e-5f + 4.0e-5f;
    }

    float rm0 = 3.4e38f, rm1 = 3.4e38f;

    // ---- staging prologue: chunk0 -> buf0; chunk1 loads in flight.
    const int4* eg4 = reinterpret_cast<const int4*>(ehg);
    int4 sa = eg4[t], sb = eg4[t + 512];
    EH4[0][t] = sa; EH4[0][t + 512] = sb;
    if (NCHUNKS > 1) { sa = eg4[1024 + t]; sb = eg4[1024 + t + 512]; }
    __syncthreads();

    int p = 0;
    for (int c = 0; c < NCHUNKS; ++c) {
        if (c + 1 < NCHUNKS) {
            // buf p^1 was last read in chunk c-1; barrier since then -> safe.
            EH4[p^1][t] = sa; EH4[p^1][t + 512] = sb;
            if (c + 2 < NCHUNKS) {
                sa = eg4[(c+2)*1024 + t]; sb = eg4[(c+2)*1024 + t + 512];
            }
        }
        #pragma unroll
        for (int lt = 0; lt < 8; ++lt) {
            const int krow = lt*16 + c16;
            // A-operand = e-tile (A[m][kd], m=lane&15=e-row: same b128 reads as R8)
            short8 ea0 = *reinterpret_cast<const short8*>(&EH4[p][(g    )*128 + krow]);
            short8 ea1 = *reinterpret_cast<const short8*>(&EH4[p][(g + 4)*128 + krow]);
            const int kb = c*KCHUNK + lt*16 + 4*g;   // this lane's 4 k-values
            f32x4 sm4 = *reinterpret_cast<const f32x4*>(&SUME[kb]);
            f32x4 a0 = {0.f,0.f,0.f,0.f}, a1 = {0.f,0.f,0.f,0.f};
            a0 = __builtin_amdgcn_mfma_f32_16x16x32_bf16(ea0, ah[0][0], a0, 0,0,0);
            a1 = __builtin_amdgcn_mfma_f32_16x16x32_bf16(ea0, ah[1][0], a1, 0,0,0);
            a0 = __builtin_amdgcn_mfma_f32_16x16x32_bf16(ea1, ah[0][1], a0, 0,0,0);
            a1 = __builtin_amdgcn_mfma_f32_16x16x32_bf16(ea1, ah[1][1], a1, 0,0,0);
            // s~ = sume - dot; D[k][x-row]: reg r -> k = kb + r, col c16 -> x-row.
            float s00 = sm4[0]-a0[0], s01 = sm4[1]-a0[1],
                  s02 = sm4[2]-a0[2], s03 = sm4[3]-a0[3];
            float s10 = sm4[0]-a1[0], s11 = sm4[1]-a1[1],
                  s12 = sm4[2]-a1[2], s13 = sm4[3]-a1[3];
            rm0 = fminf(rm0, fminf(fminf(s00,s01), fminf(s02,s03)));
            rm1 = fminf(rm1, fminf(fminf(s10,s11), fminf(s12,s13)));
            // tighten per-row runmin across the 4 owner lanes (xor 16,32 group)
            rm0 = fminf(rm0, __shfl_xor(rm0, 16));
            rm0 = fminf(rm0, __shfl_xor(rm0, 32));
            rm1 = fminf(rm1, __shfl_xor(rm1, 16));
            rm1 = fminf(rm1, __shfl_xor(rm1, 32));
            // online candidate test (superset of final-threshold set)
            const float t0 = rm0 + thr[0], t1 = rm1 + thr[1];
            const int row0 = (w*32 +      c16) << 10;
            const int row1 = (w*32 + 16 + c16) << 10;
            if (s00 < t0) { unsigned q = atomicAdd(&WCNT,1u); if (q < WCAP) WL[q] = row0 | (kb+0); }
            if (s01 < t0) { unsigned q = atomicAdd(&WCNT,1u); if (q < WCAP) WL[q] = row0 | (kb+1); }
            if (s02 < t0) { unsigned q = atomicAdd(&WCNT,1u); if (q < WCAP) WL[q] = row0 | (kb+2); }
            if (s03 < t0) { unsigned q = atomicAdd(&WCNT,1u); if (q < WCAP) WL[q] = row0 | (kb+3); }
            if (s10 < t1) { unsigned q = atomicAdd(&WCNT,1u); if (q < WCAP) WL[q] = row1 | (kb+0); }
            if (s11 < t1) { unsigned q = atomicAdd(&WCNT,1u); if (q < WCAP) WL[q] = row1 | (kb+1); }
            if (s12 < t1) { unsigned q = atomicAdd(&WCNT,1u); if (q < WCAP) WL[q] = row1 | (kb+2); }
            if (s13 < t1) { unsigned q = atomicAdd(&WCNT,1u); if (q < WCAP) WL[q] = row1 | (kb+3); }
        }
        __syncthreads();
        p ^= 1;
    }

    const unsigned wc = WCNT;                 // uniform (post-barrier)
    float* WLD = reinterpret_cast<float*>(EH4);   // reuse dead staging LDS

    if (wc <= WCAP) {
        // lane-parallel BIT-EXACT rescore (~13 pairs/row expected -> ~6/thread).
        for (unsigned q = t; q < wc; q += THREADS) {
            int pr = WL[q]; int row = pr >> 10; int kk = pr & 1023;
            const float* xr = x + (blk_row0 + (size_t)row) * EMB_DIM;
            const float* er = emb + (kk << 6);
            float sumx = np_sq64(xr);
            float cc = 0.f;
            #pragma unroll 8
            for (int i = 0; i < EMB_DIM; ++i)
                cc = fmaf(2.0f * xr[i], er[i], cc);   // sgemm sequential-k order
            float d;
            {
                #pragma clang fp contract(off)
                d = (sumx + SUME[kk]) - cc;           // fl32 grid @ ~64
            }
            WLD[q] = d;
            atomicMin(&DMIN[row], fkey(d));
        }
        __syncthreads();
        for (unsigned q = t; q < wc; q += THREADS) {
            int pr = WL[q]; int row = pr >> 10; int kk = pr & 1023;
            if (fkey(WLD[q]) == DMIN[row])
                atomicMin(&KMIN[row], (unsigned)kk);  // ties -> smallest k = first-min
        }
        __syncthreads();
        if (t < ROWS_PB) {
            int bk = (int)KMIN[t];
            SIDX[t] = bk;
            out_idx[blk_row0 + t] = (float)bk;
        }
    } else {
        // cold exact fallback (worklist overflow; never on sane data).
        if (t < ROWS_PB) {
            const float* xr = x + (blk_row0 + (size_t)t) * EMB_DIM;
            float sumx = np_sq64(xr);
            volatile const float* xv = xr;
            float bm = 3.4e38f; int bb = 0;
            for (int kk = 0; kk < NUM_EMB; ++kk) {
                const float* er = emb + (kk << 6);
                float cc = 0.f;
                for (int i = 0; i < EMB_DIM; ++i)
                    cc = fmaf(2.0f * xv[i], er[i], cc);
                {
                    #pragma clang fp contract(off)
                    float d = (sumx + SUME[kk]) - cc;
                    if (d < bm) { bm = d; bb = kk; }
                }
            }
            SIDX[t] = bb;
            out_idx[blk_row0 + t] = (float)bb;
        }
    }
    __syncthreads();

    // ---- coalesced gather: quantized[row] = emb[idx[row]]
    const float4* emb4 = reinterpret_cast<const float4*>(emb);
    float4* q4 = reinterpret_cast<float4*>(out_q + blk_row0 * EMB_DIM);
    #pragma unroll
    for (int i = 0; i < 8; ++i) {
        int e4 = t + i * THREADS;     // 4096 float4 per block
        int rr = e4 >> 4, cc2 = e4 & 15;
        q4[e4] = emb4[SIDX[rr]*16 + cc2];
    }
}

extern "C" void kernel_launch(void* const* d_in, const int* in_sizes, int n_in,
                              void* d_out, int out_size, void* d_ws, size_t ws_size,
                              hipStream_t stream) {
    const float* x   = (const float*)d_in[0];
    const float* emb = (const float*)d_in[1];
    float* out_q   = (float*)d_out;
    float* out_idx = out_q + Q_ELEMS;
    float*          sume = (float*)d_ws;                          // 4 KB
    unsigned short* ehg  = (unsigned short*)((char*)d_ws + 4096); // 128 KB bf16 emb

    vq_prep<<<dim3(NUM_EMB / 256), dim3(256), 0, stream>>>(emb, sume, ehg);
    vq_main<<<dim3(N_ROWS / ROWS_PB), dim3(THREADS), 0, stream>>>(x, emb, sume, ehg,
                                                                  out_q, out_idx);
}

// Round 10
// 83.166 us; speedup vs baseline: 1.6302x; 1.6302x over previous
//
#include <hip/hip_runtime.h>

// VQ-VAE quantize. Output BIT-EXACT vs numpy fp32 pipeline (proven R3-R9):
//   d_k = fl32( fl32(sumx + sume_k) - c_k ), c_k = sequential-k fp32 FMA of (2x).e,
//   idx = first-minimum argmin.
//
// R10 = R8's two-sweep prefilter (A: exact f32 per-row min of s~; B: recompute s~
// deterministically, worklist s~ < RMIN + W; lane-parallel bit-exact rescore)
// re-geometried for occupancy:
//   - 8 waves x 16 rows (ROWS_PB=128) -> grid 1024 = 4 blocks/CU (was 2, grid-capped)
//   - __launch_bounds__(512,8): VGPR<=64 -> 32 waves/CU possible
//   - single-buffer EH4 (16KB, LDS ~29KB) + async-split staging: next chunk's
//     global loads issued right after the post-write barrier, ds_written next chunk
// Candidate detection stays OUT of the MFMA critical path (R9 lesson: in-loop
// shfl/atomic chains killed MFMA pipelining -> MfmaUtil 4.6%).

#define N_ROWS   131072
#define NUM_EMB  1024
#define EMB_DIM  64
#define Q_ELEMS  8388608
#define THREADS  512
#define ROWS_PB  128          // 8 waves x 16 rows
#define KCHUNK   128
#define NCHUNKS  8
#define WCAP     1024

typedef short short8 __attribute__((ext_vector_type(8)));
typedef float f32x4  __attribute__((ext_vector_type(4)));

__device__ __forceinline__ unsigned short bf16_rne(float f) {
    unsigned u = __float_as_uint(f);
    u += 0x7fffu + ((u >> 16) & 1u);
    return (unsigned short)(u >> 16);
}

// monotone key for f32 (handles negatives): smaller float -> smaller key
__device__ __forceinline__ unsigned fkey(float d) {
    unsigned b = __float_as_uint(d);
    return b ^ (((unsigned)((int)b >> 31)) | 0x80000000u);
}

// numpy pairwise_sum (n=64) of fl32(a[i]*a[i]) — 8-accumulator order.
__device__ __forceinline__ float np_sq64(const float* a) {
    #pragma clang fp contract(off)
    float r0=a[0]*a[0],r1=a[1]*a[1],r2=a[2]*a[2],r3=a[3]*a[3];
    float r4=a[4]*a[4],r5=a[5]*a[5],r6=a[6]*a[6],r7=a[7]*a[7];
    #pragma unroll
    for (int i=8;i<64;i+=8){
        r0+=a[i+0]*a[i+0];r1+=a[i+1]*a[i+1];r2+=a[i+2]*a[i+2];r3+=a[i+3]*a[i+3];
        r4+=a[i+4]*a[i+4];r5+=a[i+5]*a[i+5];r6+=a[i+6]*a[i+6];r7+=a[i+7]*a[i+7];
    }
    return ((r0+r1)+(r2+r3))+((r4+r5)+(r6+r7));
}

// min over the 16 lanes of each DPP row (row_ror 1,2,4,8) — R7/R8-verified.
__device__ __forceinline__ float rotmin16(float v) {
    int x;
    x = __builtin_amdgcn_update_dpp(0, __float_as_int(v), 0x121, 0xf, 0xf, true);
    v = fminf(v, __int_as_float(x));
    x = __builtin_amdgcn_update_dpp(0, __float_as_int(v), 0x122, 0xf, 0xf, true);
    v = fminf(v, __int_as_float(x));
    x = __builtin_amdgcn_update_dpp(0, __float_as_int(v), 0x124, 0xf, 0xf, true);
    v = fminf(v, __int_as_float(x));
    x = __builtin_amdgcn_update_dpp(0, __float_as_int(v), 0x128, 0xf, 0xf, true);
    v = fminf(v, __int_as_float(x));
    return v;
}

// prep: sume (np order) + emb -> bf16, layout unit = chunk*1024 + gp*128 + krow
// (unit = 8 bf16 of dims gp*8..gp*8+7). Unchanged from R8 (verified).
__global__ __launch_bounds__(256) void vq_prep(const float* __restrict__ emb,
                                               float* __restrict__ sume,
                                               unsigned short* __restrict__ ehg) {
    int k = blockIdx.x * 256 + threadIdx.x;
    if (k < NUM_EMB) {
        sume[k] = np_sq64(emb + (k << 6));
        int c = k >> 7, krow = k & 127;
        #pragma unroll
        for (int gp = 0; gp < 8; ++gp) {
            short8 h;
            #pragma unroll
            for (int j = 0; j < 8; ++j)
                h[j] = (short)bf16_rne(emb[(k << 6) + gp*8 + j]);
            reinterpret_cast<short8*>(ehg)[c*1024 + gp*128 + krow] = h;
        }
    }
}

__global__ __launch_bounds__(THREADS, 8)
void vq_main(const float* __restrict__ x, const float* __restrict__ emb,
             const float* __restrict__ sume_g, const unsigned short* __restrict__ ehg,
             float* __restrict__ out_q, float* __restrict__ out_idx) {
    __shared__ int4     EH4[1024];        // 16 KB: current bf16 e-chunk
    __shared__ float    SUME[NUM_EMB];    // 4 KB
    __shared__ float    RMIN[ROWS_PB];
    __shared__ float    THR[ROWS_PB];
    __shared__ float    SA[ROWS_PB];
    __shared__ int      WL[WCAP];         // 4 KB worklist (row<<10 | k)
    __shared__ unsigned DMIN[ROWS_PB];
    __shared__ unsigned KMIN[ROWS_PB];
    __shared__ int      SIDX[ROWS_PB];
    __shared__ unsigned WCNT;

    const int t   = threadIdx.x;
    const int w   = t >> 6;          // wave 0..7: owns rows w*16..w*16+15
    const int l   = t & 63;
    const int g   = l >> 4;          // k-dim quarter 0..3
    const int c16 = l & 15;
    const size_t blk_row0 = (size_t)blockIdx.x * ROWS_PB;

    // issue sweep-A chunk-0 staging loads first (latency hides under setup)
    const int4* eg4 = reinterpret_cast<const int4*>(ehg);
    int4 sa = eg4[t], sb = eg4[t + 512];

    SUME[t]       = sume_g[t];
    SUME[t + 512] = sume_g[t + 512];
    if (t < ROWS_PB) { DMIN[t] = 0xFFFFFFFFu; KMIN[t] = 0xFFFFFFFFu; }
    if (t == 0) WCNT = 0u;

    // ---- A-frag (x, 2.0 folded): A[m][kd], m = lane&15 = x-row (R8-verified);
    // per-row SA = sum|2x| reduced across the 4 g-lanes.
    short8 ah[2];
    {
        const float* xp = x + (blk_row0 + (size_t)(w*16 + c16)) * EMB_DIM;
        float sabs = 0.f;
        #pragma unroll
        for (int hf = 0; hf < 2; ++hf) {
            #pragma unroll
            for (int j = 0; j < 8; ++j) {
                float v = 2.0f * xp[hf*32 + g*8 + j];
                sabs += fabsf(v);
                ah[hf][j] = (short)bf16_rne(v);
            }
        }
        sabs += __shfl_xor(sabs, 16);
        sabs += __shfl_xor(sabs, 32);
        if (g == 0) SA[w*16 + c16] = sabs;
    }

    // ---- sweep A: exact f32 running min of s~ per (reg); no shfl/atomics in loop.
    float stash[4] = {3.4e38f, 3.4e38f, 3.4e38f, 3.4e38f};

    for (int c = 0; c < NCHUNKS; ++c) {
        EH4[t] = sa; EH4[t + 512] = sb;            // buffer free (barrier at loop end)
        __syncthreads();
        if (c + 1 < NCHUNKS) {                     // async: hides under compute
            sa = eg4[(c+1)*1024 + t]; sb = eg4[(c+1)*1024 + t + 512];
        }
        #pragma unroll
        for (int lt = 0; lt < 8; ++lt) {
            const int krow = lt*16 + c16;
            short8 bh0 = reinterpret_cast<const short8*>(EH4)[(g    )*128 + krow];
            short8 bh1 = reinterpret_cast<const short8*>(EH4)[(g + 4)*128 + krow];
            float scol = SUME[c*KCHUNK + krow];
            f32x4 a0 = {0.f,0.f,0.f,0.f};
            a0 = __builtin_amdgcn_mfma_f32_16x16x32_bf16(ah[0], bh0, a0, 0,0,0);
            a0 = __builtin_amdgcn_mfma_f32_16x16x32_bf16(ah[1], bh1, a0, 0,0,0);
            #pragma unroll
            for (int r = 0; r < 4; ++r)
                stash[r] = fminf(stash[r], scol - a0[r]);
        }
        __syncthreads();
    }

    // D-row = 4*g + r (R8-verified); reduce cols via rotmin16, publish RMIN/THR.
    #pragma unroll
    for (int r = 0; r < 4; ++r) {
        float v = rotmin16(stash[r]);
        if (c16 == 0) RMIN[w*16 + 4*g + r] = v;
    }
    __syncthreads();
    if (t < ROWS_PB) {
        // W = SA*2^-16 (two-sided bf16 product err, conservative) + grid/acc slack
        THR[t] = RMIN[t] + (SA[t] * 1.6e-5f + 4.0e-5f);
    }
    __syncthreads();
    float thrv[4];
    #pragma unroll
    for (int r = 0; r < 4; ++r) thrv[r] = THR[w*16 + 4*g + r];

    // ---- sweep B: recompute s~ (bit-identical), append candidates.
    sa = eg4[t]; sb = eg4[t + 512];
    for (int c = 0; c < NCHUNKS; ++c) {
        EH4[t] = sa; EH4[t + 512] = sb;
        __syncthreads();
        if (c + 1 < NCHUNKS) {
            sa = eg4[(c+1)*1024 + t]; sb = eg4[(c+1)*1024 + t + 512];
        }
        #pragma unroll
        for (int lt = 0; lt < 8; ++lt) {
            const int krow = lt*16 + c16;
            short8 bh0 = reinterpret_cast<const short8*>(EH4)[(g    )*128 + krow];
            short8 bh1 = reinterpret_cast<const short8*>(EH4)[(g + 4)*128 + krow];
            float scol = SUME[c*KCHUNK + krow];
            f32x4 a0 = {0.f,0.f,0.f,0.f};
            a0 = __builtin_amdgcn_mfma_f32_16x16x32_bf16(ah[0], bh0, a0, 0,0,0);
            a0 = __builtin_amdgcn_mfma_f32_16x16x32_bf16(ah[1], bh1, a0, 0,0,0);
            const int kk = c*KCHUNK + krow;
            #pragma unroll
            for (int r = 0; r < 4; ++r) {
                float sv = scol - a0[r];
                if (sv < thrv[r]) {
                    unsigned q = atomicAdd(&WCNT, 1u);
                    if (q < WCAP) WL[q] = ((w*16 + 4*g + r) << 10) | kk;
                }
            }
        }
        __syncthreads();
    }

    const unsigned wc = WCNT;                      // uniform (post-barrier)
    float* WLD = reinterpret_cast<float*>(EH4);    // staging LDS is dead: reuse

    if (wc <= WCAP) {
        // lane-parallel BIT-EXACT rescore (~1.5 pairs/row expected).
        for (unsigned q = t; q < wc; q += THREADS) {
            int pr = WL[q]; int row = pr >> 10; int kk = pr & 1023;
            const float* xr = x + (blk_row0 + (size_t)row) * EMB_DIM;
            const float* er = emb + (kk << 6);
            float sumx = np_sq64(xr);
            float cc = 0.f;
            #pragma unroll 8
            for (int i = 0; i < EMB_DIM; ++i)
                cc = fmaf(2.0f * xr[i], er[i], cc);   // sgemm sequential-k order
            float d;
            {
                #pragma clang fp contract(off)
                d = (sumx + SUME[kk]) - cc;           // fl32 grid @ ~64
            }
            WLD[q] = d;
            atomicMin(&DMIN[row], fkey(d));
        }
        __syncthreads();
        for (unsigned q = t; q < wc; q += THREADS) {
            int pr = WL[q]; int row = pr >> 10; int kk = pr & 1023;
            if (fkey(WLD[q]) == DMIN[row])
                atomicMin(&KMIN[row], (unsigned)kk);  // ties -> smallest k = first-min
        }
        __syncthreads();
        if (t < ROWS_PB) {
            int bk = (int)KMIN[t];
            SIDX[t] = bk;
            out_idx[blk_row0 + t] = (float)bk;
        }
    } else {
        // cold exact fallback (worklist overflow; never on sane data).
        if (t < ROWS_PB) {
            const float* xr = x + (blk_row0 + (size_t)t) * EMB_DIM;
            float sumx = np_sq64(xr);
            volatile const float* xv = xr;
            float bm = 3.4e38f; int bb = 0;
            for (int kk = 0; kk < NUM_EMB; ++kk) {
                const float* er = emb + (kk << 6);
                float cc = 0.f;
                for (int i = 0; i < EMB_DIM; ++i)
                    cc = fmaf(2.0f * xv[i], er[i], cc);
                {
                    #pragma clang fp contract(off)
                    float d = (sumx + SUME[kk]) - cc;
                    if (d < bm) { bm = d; bb = kk; }
                }
            }
            SIDX[t] = bb;
            out_idx[blk_row0 + t] = (float)bb;
        }
    }
    __syncthreads();

    // ---- coalesced gather: quantized[row] = emb[idx[row]]
    const float4* emb4 = reinterpret_cast<const float4*>(emb);
    float4* q4 = reinterpret_cast<float4*>(out_q + blk_row0 * EMB_DIM);
    #pragma unroll
    for (int i = 0; i < 4; ++i) {
        int e4 = t + i * THREADS;     // 2048 float4 per block
        int rr = e4 >> 4, cc2 = e4 & 15;
        q4[e4] = emb4[SIDX[rr]*16 + cc2];
    }
}

extern "C" void kernel_launch(void* const* d_in, const int* in_sizes, int n_in,
                              void* d_out, int out_size, void* d_ws, size_t ws_size,
                              hipStream_t stream) {
    const float* x   = (const float*)d_in[0];
    const float* emb = (const float*)d_in[1];
    float* out_q   = (float*)d_out;
    float* out_idx = out_q + Q_ELEMS;
    float*          sume = (float*)d_ws;                          // 4 KB
    unsigned short* ehg  = (unsigned short*)((char*)d_ws + 4096); // 128 KB bf16 emb

    vq_prep<<<dim3(NUM_EMB / 256), dim3(256), 0, stream>>>(emb, sume, ehg);
    vq_main<<<dim3(N_ROWS / ROWS_PB), dim3(THREADS), 0, stream>>>(x, emb, sume, ehg,
                                                                  out_q, out_idx);
}